// Round 8
// baseline (217.329 us; speedup 1.0000x reference)
//
#include <hip/hip_runtime.h>

#define NN 50000
#define TOPK 32
#define IN_C 128
#define OUT_C 64
#define NEG_SLOPE 0.2f
#define BN_EPS 1e-5f

// K1: MFMA, 16 nodes per block
#define K1_BLOCKS (NN / 16)         // 3125

// K2a/K2b: 4 nodes per wave, 16 lanes per node
#define K2_BLOCKS (NN / 16)         // 3125 blocks x 4 waves x 4 nodes

// workspace layout (floats)
#define WS_XBF   0                       // bf16 x_lin: NN*64*2B
#define WS_AI    (NN * 32)
#define WS_AJ    (WS_AI + NN)
#define WS_SUMS  (WS_AJ + NN)            // 128

typedef __bf16 bf16x8 __attribute__((ext_vector_type(8)));
typedef float f32x4 __attribute__((ext_vector_type(4)));
union BF8 { unsigned short u[8]; bf16x8 v; };

__device__ inline float leaky(float a) { return a >= 0.f ? a : NEG_SLOPE * a; }
__device__ inline float bl(unsigned u) { return __uint_as_float(u << 16); }
__device__ inline float bh(unsigned u) { return __uint_as_float(u & 0xffff0000u); }

__device__ inline unsigned short f2bf(float f) {     // RNE fp32 -> bf16
    unsigned u = __float_as_uint(f);
    unsigned r = (u + 0x7fffu + ((u >> 16) & 1u)) >> 16;
    return (unsigned short)r;
}

// K1: x_lin(bf16) = x @ lin_w^T via MFMA 16x16x32_bf16 + a_i/a_j epilogue.
__global__ __launch_bounds__(256) void k1_mfma(
    const float* __restrict__ x, const float* __restrict__ emb,
    const float* __restrict__ lin_w,
    const float* __restrict__ att_i, const float* __restrict__ att_j,
    const float* __restrict__ att_em_i, const float* __restrict__ att_em_j,
    unsigned short* __restrict__ x_bf, float* __restrict__ a_i,
    float* __restrict__ a_j, float* __restrict__ sums)
{
    __shared__ float redi[16][5], redj[16][5];
    __shared__ float eredi[16][17], eredj[16][17];
    const int tid = threadIdx.x;
    if (blockIdx.x == 0 && tid < 128) sums[tid] = 0.f;

    const int lane = tid & 63;
    const int wv = tid >> 6;
    const int quad = lane >> 4;
    const int nn = lane & 15;
    const int base = blockIdx.x * 16;
    const int c = wv * 16 + nn;          // this lane's output channel

    BF8 bfr[4], afr[4];
    {
        const float* wr = lin_w + (size_t)c * IN_C + quad * 8;
        const float* xr = x + (size_t)(base + nn) * IN_C + quad * 8;
#pragma unroll
        for (int s = 0; s < 4; ++s) {
            const float4 wa = *(const float4*)(wr + s * 32);
            const float4 wb = *(const float4*)(wr + s * 32 + 4);
            const float4 xa = *(const float4*)(xr + s * 32);
            const float4 xb = *(const float4*)(xr + s * 32 + 4);
            bfr[s].u[0] = f2bf(wa.x); bfr[s].u[1] = f2bf(wa.y);
            bfr[s].u[2] = f2bf(wa.z); bfr[s].u[3] = f2bf(wa.w);
            bfr[s].u[4] = f2bf(wb.x); bfr[s].u[5] = f2bf(wb.y);
            bfr[s].u[6] = f2bf(wb.z); bfr[s].u[7] = f2bf(wb.w);
            afr[s].u[0] = f2bf(xa.x); afr[s].u[1] = f2bf(xa.y);
            afr[s].u[2] = f2bf(xa.z); afr[s].u[3] = f2bf(xa.w);
            afr[s].u[4] = f2bf(xb.x); afr[s].u[5] = f2bf(xb.y);
            afr[s].u[6] = f2bf(xb.z); afr[s].u[7] = f2bf(xb.w);
        }
    }

    f32x4 acc = {0.f, 0.f, 0.f, 0.f};
#pragma unroll
    for (int s = 0; s < 4; ++s)
        acc = __builtin_amdgcn_mfma_f32_16x16x32_bf16(afr[s].v, bfr[s].v, acc,
                                                      0, 0, 0);

    const float aic = att_i[c], ajc = att_j[c];
    float pi[4], pj[4];
#pragma unroll
    for (int r = 0; r < 4; ++r) {
        const int node = base + quad * 4 + r;
        x_bf[(size_t)node * OUT_C + c] = f2bf(acc[r]);
        pi[r] = acc[r] * aic;
        pj[r] = acc[r] * ajc;
    }
#pragma unroll
    for (int d = 1; d < 16; d <<= 1) {
#pragma unroll
        for (int r = 0; r < 4; ++r) {
            pi[r] += __shfl_xor(pi[r], d, 64);
            pj[r] += __shfl_xor(pj[r], d, 64);
        }
    }
    if (nn == 0) {
#pragma unroll
        for (int r = 0; r < 4; ++r) {
            redi[quad * 4 + r][wv] = pi[r];
            redj[quad * 4 + r][wv] = pj[r];
        }
    }
    {
        const int nl = tid >> 4, c4 = tid & 15;
        const float4 e4 = ((const float4*)emb)[(size_t)(base + nl) * 16 + c4];
        const float4 i4 = ((const float4*)att_em_i)[c4];
        const float4 j4 = ((const float4*)att_em_j)[c4];
        eredi[nl][c4] = e4.x * i4.x + e4.y * i4.y + e4.z * i4.z + e4.w * i4.w;
        eredj[nl][c4] = e4.x * j4.x + e4.y * j4.y + e4.z * j4.z + e4.w * j4.w;
    }
    __syncthreads();
    if (tid < 16) {
        float si = redi[tid][0] + redi[tid][1] + redi[tid][2] + redi[tid][3];
        float sj = redj[tid][0] + redj[tid][1] + redj[tid][2] + redj[tid][3];
#pragma unroll
        for (int r = 0; r < 16; ++r) { si += eredi[tid][r]; sj += eredj[tid][r]; }
        a_i[base + tid] = si;
        a_j[base + tid] = sj;
    }
}

// K2a: softmax weights only. 16 lanes/node: lane q handles edges q, q+16;
// self edge handled redundantly. Writes 33 normalized weights into the
// node's own d_out row (first 132 of 256 B) for K2b to consume.
__global__ __launch_bounds__(256) void k2a_softmax(
    const int* __restrict__ src, const float* __restrict__ a_i,
    const float* __restrict__ a_j, float* __restrict__ out)
{
    const int tid = threadIdx.x;
    const int lane = tid & 63;
    const int wv = tid >> 6;
    const int g = lane >> 4;
    const int q = lane & 15;
    const int t = (blockIdx.x * 4 + wv) * 4 + g;    // [0, 50000) exact

    const float ai_t = a_i[t];
    const int s0 = src[(size_t)t * TOPK + q];
    const int s1 = src[(size_t)t * TOPK + 16 + q];
    const float l0 = leaky(ai_t + a_j[s0]);
    const float l1 = leaky(ai_t + a_j[s1]);
    const float ls = leaky(ai_t + a_j[t]);          // self (broadcast)

    float m = fmaxf(l0, l1);
#pragma unroll
    for (int d = 1; d < 16; d <<= 1) m = fmaxf(m, __shfl_xor(m, d, 64));
    m = fmaxf(m, ls);
    const float e0 = __expf(l0 - m);
    const float e1 = __expf(l1 - m);
    const float es = __expf(ls - m);
    float den = e0 + e1;
#pragma unroll
    for (int d = 1; d < 16; d <<= 1) den += __shfl_xor(den, d, 64);
    den += es + 1e-16f;
    const float inv = 1.f / den;

    float* wrow = out + (size_t)t * OUT_C;
    wrow[q] = e0 * inv;
    wrow[16 + q] = e1 * inv;
    if (q == 0) wrow[32] = es * inv;
}

// K2b: pure gather-aggregate. Weights come from the node's out row as 9
// contiguous broadcast loads; 33 bf16-row gathers + fp32 fma; overwrites
// the out row; accumulates BN partials.
__global__ __launch_bounds__(256, 2) void k2b_agg(
    const int* __restrict__ src, const uint2* __restrict__ x_bf2,
    const float* __restrict__ bias, float* out, float* __restrict__ sums)
{
    const int tid = threadIdx.x;
    const int lane = tid & 63;
    const int wv = tid >> 6;
    const int g = lane >> 4;
    const int q = lane & 15;
    const int t = (blockIdx.x * 4 + wv) * 4 + g;    // [0, 50000) exact
    const float4 b4 = ((const float4*)bias)[q];

    const float* wrow = out + (size_t)t * OUT_C;
    float4 w4[8];
#pragma unroll
    for (int i = 0; i < 8; ++i) w4[i] = ((const float4*)wrow)[i];
    const float wself = wrow[32];

    const int4* sp4 = (const int4*)(src + (size_t)t * TOPK);
    float A0 = 0.f, A1 = 0.f, A2 = 0.f, A3 = 0.f;
#define ACC4(U, W)                                                            \
    { A0 = fmaf(W, bl(U.x), A0); A1 = fmaf(W, bh(U.x), A1);                   \
      A2 = fmaf(W, bl(U.y), A2); A3 = fmaf(W, bh(U.y), A3); }
#pragma unroll
    for (int i = 0; i < 8; ++i) {
        const int4 s4 = sp4[i];
        const uint2 u0 = x_bf2[(size_t)s4.x * 16 + q];
        const uint2 u1 = x_bf2[(size_t)s4.y * 16 + q];
        const uint2 u2 = x_bf2[(size_t)s4.z * 16 + q];
        const uint2 u3 = x_bf2[(size_t)s4.w * 16 + q];
        ACC4(u0, w4[i].x); ACC4(u1, w4[i].y);
        ACC4(u2, w4[i].z); ACC4(u3, w4[i].w);
    }
    {
        const uint2 us = x_bf2[(size_t)t * 16 + q];
        ACC4(us, wself);
    }
#undef ACC4
    const float v0 = A0 + b4.x, v1 = A1 + b4.y;
    const float v2 = A2 + b4.z, v3 = A3 + b4.w;
    ((float4*)out)[(size_t)t * 16 + q] = make_float4(v0, v1, v2, v3);

    // block BN reduction: channel c = q*4+j, slot = wv*4+g (16 slots)
    __shared__ float sb1[64][17];
    __shared__ float sb2[64][17];
    const int slot = wv * 4 + g;
    sb1[q * 4 + 0][slot] = v0; sb1[q * 4 + 1][slot] = v1;
    sb1[q * 4 + 2][slot] = v2; sb1[q * 4 + 3][slot] = v3;
    sb2[q * 4 + 0][slot] = v0 * v0; sb2[q * 4 + 1][slot] = v1 * v1;
    sb2[q * 4 + 2][slot] = v2 * v2; sb2[q * 4 + 3][slot] = v3 * v3;
    __syncthreads();
    if (tid < 64) {
        float t1 = 0.f, t2 = 0.f;
#pragma unroll
        for (int r = 0; r < 16; ++r) { t1 += sb1[tid][r]; t2 += sb2[tid][r]; }
        atomicAdd(&sums[tid], t1);
        atomicAdd(&sums[64 + tid], t2);
    }
}

// K4: BN stats computed redundantly per block from sums, then apply + ReLU.
__global__ __launch_bounds__(256) void k4_bn(
    float* __restrict__ out, const float* __restrict__ sums,
    const float* __restrict__ gamma, const float* __restrict__ beta)
{
    __shared__ float s_sc[64], s_sh[64];
    const int tid = threadIdx.x;
    if (tid < 64) {
        const float mu = sums[tid] / (float)NN;
        const float ex2 = sums[64 + tid] / (float)NN;
        const float var = fmaxf(ex2 - mu * mu, 0.f);
        const float sc = gamma[tid] / sqrtf(var + BN_EPS);
        s_sc[tid] = sc;
        s_sh[tid] = beta[tid] - mu * sc;
    }
    __syncthreads();
    const int total = NN * OUT_C / 4;
    float4* p = (float4*)out;
    for (int idx = blockIdx.x * 256 + tid; idx < total; idx += gridDim.x * 256) {
        float4 v = p[idx];
        const int c0 = (idx & 15) * 4;
        v.x = fmaxf(fmaf(v.x, s_sc[c0 + 0], s_sh[c0 + 0]), 0.f);
        v.y = fmaxf(fmaf(v.y, s_sc[c0 + 1], s_sh[c0 + 1]), 0.f);
        v.z = fmaxf(fmaf(v.z, s_sc[c0 + 2], s_sh[c0 + 2]), 0.f);
        v.w = fmaxf(fmaf(v.w, s_sc[c0 + 3], s_sh[c0 + 3]), 0.f);
        p[idx] = v;
    }
}

extern "C" void kernel_launch(void* const* d_in, const int* in_sizes, int n_in,
                              void* d_out, int out_size, void* d_ws, size_t ws_size,
                              hipStream_t stream) {
    const float* x        = (const float*)d_in[0];
    const float* emb      = (const float*)d_in[1];
    const int*   edge     = (const int*)d_in[2];   // row 0 = src
    const float* lin_w    = (const float*)d_in[3];
    const float* att_i    = (const float*)d_in[4];
    const float* att_j    = (const float*)d_in[5];
    const float* att_em_i = (const float*)d_in[6];
    const float* att_em_j = (const float*)d_in[7];
    const float* bias     = (const float*)d_in[8];
    const float* gamma    = (const float*)d_in[9];
    const float* beta     = (const float*)d_in[10];

    float* ws    = (float*)d_ws;
    unsigned short* x_bf = (unsigned short*)(ws + WS_XBF);
    float* a_i   = ws + WS_AI;
    float* a_j   = ws + WS_AJ;
    float* sums  = ws + WS_SUMS;
    float* out   = (float*)d_out;

    k1_mfma<<<K1_BLOCKS, 256, 0, stream>>>(x, emb, lin_w, att_i, att_j,
                                           att_em_i, att_em_j, x_bf, a_i, a_j, sums);
    k2a_softmax<<<K2_BLOCKS, 256, 0, stream>>>(edge, a_i, a_j, out);
    k2b_agg<<<K2_BLOCKS, 256, 0, stream>>>(edge, (const uint2*)x_bf, bias, out, sums);
    k4_bn<<<1024, 256, 0, stream>>>(out, sums, gamma, beta);
}

// Round 9
// 209.255 us; speedup vs baseline: 1.0386x; 1.0386x over previous
//
#include <hip/hip_runtime.h>

#define NN 50000
#define TOPK 32
#define IN_C 128
#define OUT_C 64
#define NEG_SLOPE 0.2f
#define BN_EPS 1e-5f

// K1: MFMA, 16 nodes per block
#define K1_BLOCKS (NN / 16)         // 3125

// K2: 4 nodes per wave (16 lanes/node), 1 task per wave
#define K2_BLOCKS (NN / 16)         // 3125

// workspace layout (floats)
#define WS_XBF   0                       // bf16 x_lin: NN*64*2B
#define WS_AI    (NN * 32)
#define WS_AJ    (WS_AI + NN)
#define WS_SUMS  (WS_AJ + NN)            // 128

typedef __bf16 bf16x8 __attribute__((ext_vector_type(8)));
typedef float f32x4 __attribute__((ext_vector_type(4)));
union BF8 { unsigned short u[8]; bf16x8 v; };

__device__ inline float leaky(float a) { return a >= 0.f ? a : NEG_SLOPE * a; }
__device__ inline float bl(unsigned u) { return __uint_as_float(u << 16); }
__device__ inline float bh(unsigned u) { return __uint_as_float(u & 0xffff0000u); }

__device__ inline unsigned short f2bf(float f) {     // RNE fp32 -> bf16
    unsigned u = __float_as_uint(f);
    unsigned r = (u + 0x7fffu + ((u >> 16) & 1u)) >> 16;
    return (unsigned short)r;
}

// K1: x_lin(bf16) = x @ lin_w^T via MFMA 16x16x32_bf16 + a_i/a_j epilogue.
// (frozen from round 7)
__global__ __launch_bounds__(256) void k1_mfma(
    const float* __restrict__ x, const float* __restrict__ emb,
    const float* __restrict__ lin_w,
    const float* __restrict__ att_i, const float* __restrict__ att_j,
    const float* __restrict__ att_em_i, const float* __restrict__ att_em_j,
    unsigned short* __restrict__ x_bf, float* __restrict__ a_i,
    float* __restrict__ a_j, float* __restrict__ sums)
{
    __shared__ float redi[16][5], redj[16][5];
    __shared__ float eredi[16][17], eredj[16][17];
    const int tid = threadIdx.x;
    if (blockIdx.x == 0 && tid < 128) sums[tid] = 0.f;

    const int lane = tid & 63;
    const int wv = tid >> 6;
    const int quad = lane >> 4;
    const int nn = lane & 15;
    const int base = blockIdx.x * 16;
    const int c = wv * 16 + nn;          // this lane's output channel

    BF8 bfr[4], afr[4];
    {
        const float* wr = lin_w + (size_t)c * IN_C + quad * 8;
        const float* xr = x + (size_t)(base + nn) * IN_C + quad * 8;
#pragma unroll
        for (int s = 0; s < 4; ++s) {
            const float4 wa = *(const float4*)(wr + s * 32);
            const float4 wb = *(const float4*)(wr + s * 32 + 4);
            const float4 xa = *(const float4*)(xr + s * 32);
            const float4 xb = *(const float4*)(xr + s * 32 + 4);
            bfr[s].u[0] = f2bf(wa.x); bfr[s].u[1] = f2bf(wa.y);
            bfr[s].u[2] = f2bf(wa.z); bfr[s].u[3] = f2bf(wa.w);
            bfr[s].u[4] = f2bf(wb.x); bfr[s].u[5] = f2bf(wb.y);
            bfr[s].u[6] = f2bf(wb.z); bfr[s].u[7] = f2bf(wb.w);
            afr[s].u[0] = f2bf(xa.x); afr[s].u[1] = f2bf(xa.y);
            afr[s].u[2] = f2bf(xa.z); afr[s].u[3] = f2bf(xa.w);
            afr[s].u[4] = f2bf(xb.x); afr[s].u[5] = f2bf(xb.y);
            afr[s].u[6] = f2bf(xb.z); afr[s].u[7] = f2bf(xb.w);
        }
    }

    f32x4 acc = {0.f, 0.f, 0.f, 0.f};
#pragma unroll
    for (int s = 0; s < 4; ++s)
        acc = __builtin_amdgcn_mfma_f32_16x16x32_bf16(afr[s].v, bfr[s].v, acc,
                                                      0, 0, 0);

    const float aic = att_i[c], ajc = att_j[c];
    float pi[4], pj[4];
#pragma unroll
    for (int r = 0; r < 4; ++r) {
        const int node = base + quad * 4 + r;
        x_bf[(size_t)node * OUT_C + c] = f2bf(acc[r]);
        pi[r] = acc[r] * aic;
        pj[r] = acc[r] * ajc;
    }
#pragma unroll
    for (int d = 1; d < 16; d <<= 1) {
#pragma unroll
        for (int r = 0; r < 4; ++r) {
            pi[r] += __shfl_xor(pi[r], d, 64);
            pj[r] += __shfl_xor(pj[r], d, 64);
        }
    }
    if (nn == 0) {
#pragma unroll
        for (int r = 0; r < 4; ++r) {
            redi[quad * 4 + r][wv] = pi[r];
            redj[quad * 4 + r][wv] = pj[r];
        }
    }
    {
        const int nl = tid >> 4, c4 = tid & 15;
        const float4 e4 = ((const float4*)emb)[(size_t)(base + nl) * 16 + c4];
        const float4 i4 = ((const float4*)att_em_i)[c4];
        const float4 j4 = ((const float4*)att_em_j)[c4];
        eredi[nl][c4] = e4.x * i4.x + e4.y * i4.y + e4.z * i4.z + e4.w * i4.w;
        eredj[nl][c4] = e4.x * j4.x + e4.y * j4.y + e4.z * j4.z + e4.w * j4.w;
    }
    __syncthreads();
    if (tid < 16) {
        float si = redi[tid][0] + redi[tid][1] + redi[tid][2] + redi[tid][3];
        float sj = redj[tid][0] + redj[tid][1] + redj[tid][2] + redj[tid][3];
#pragma unroll
        for (int r = 0; r < 16; ++r) { si += eredi[tid][r]; sj += eredj[tid][r]; }
        a_i[base + tid] = si;
        a_j[base + tid] = sj;
    }
}

// K2: combined softmax + aggregate. 4 nodes/wave (16 lanes/node, lane owns
// 4 channels), ONE task per wave. All 33 row-gathers hoisted into u[33]
// BEFORE the softmax so they overlap the alj loads and exp chain; no
// VGPR cap (launch_bounds 256 only) so the whole task stays in registers.
__global__ __launch_bounds__(256) void k2_attn(
    const int* __restrict__ src,
    const uint2* __restrict__ x_bf2, const float* __restrict__ a_i,
    const float* __restrict__ a_j, const float* __restrict__ bias,
    float* __restrict__ out, float* __restrict__ sums)
{
    const int tid = threadIdx.x;
    const int lane = tid & 63;
    const int wv = tid >> 6;
    const int g = lane >> 4;
    const int q = lane & 15;
    const int t = (blockIdx.x * 4 + wv) * 4 + g;    // [0, 50000) exact
    const float4 b4 = ((const float4*)bias)[q];

    // --- issue src loads ---
    const int4* sp4 = (const int4*)(src + (size_t)t * TOPK);
    int4 s4[8];
#pragma unroll
    for (int i = 0; i < 8; ++i) s4[i] = sp4[i];      // broadcast across 16 lanes

    // --- issue ALL row gathers (only dependence: s4) ---
    uint2 u[33];
#pragma unroll
    for (int i = 0; i < 8; ++i) {
        u[i * 4 + 0] = x_bf2[(size_t)s4[i].x * 16 + q];
        u[i * 4 + 1] = x_bf2[(size_t)s4[i].y * 16 + q];
        u[i * 4 + 2] = x_bf2[(size_t)s4[i].z * 16 + q];
        u[i * 4 + 3] = x_bf2[(size_t)s4[i].w * 16 + q];
    }
    u[32] = x_bf2[(size_t)t * 16 + q];

    // --- attention coefficients (overlaps the gathers in flight) ---
    const float ai_t = a_i[t];
    float alj[33];
#pragma unroll
    for (int i = 0; i < 8; ++i) {
        alj[i * 4 + 0] = a_j[s4[i].x];
        alj[i * 4 + 1] = a_j[s4[i].y];
        alj[i * 4 + 2] = a_j[s4[i].z];
        alj[i * 4 + 3] = a_j[s4[i].w];
    }
    alj[32] = a_j[t];

    // per-lane softmax over 33 edges (redundant across the 16-lane group)
    float mx = -1e30f;
#pragma unroll
    for (int e = 0; e < 33; ++e) {
        alj[e] = leaky(ai_t + alj[e]);
        mx = fmaxf(mx, alj[e]);
    }
    float den = 0.f;
#pragma unroll
    for (int e = 0; e < 33; ++e) { alj[e] = __expf(alj[e] - mx); den += alj[e]; }
    const float inv = 1.f / (den + 1e-16f);

    // --- weighted accumulate ---
    float A0 = 0.f, A1 = 0.f, A2 = 0.f, A3 = 0.f;
#pragma unroll
    for (int e = 0; e < 33; ++e) {
        const float w = alj[e] * inv;
        A0 = fmaf(w, bl(u[e].x), A0);
        A1 = fmaf(w, bh(u[e].x), A1);
        A2 = fmaf(w, bl(u[e].y), A2);
        A3 = fmaf(w, bh(u[e].y), A3);
    }
    const float v0 = A0 + b4.x, v1 = A1 + b4.y;
    const float v2 = A2 + b4.z, v3 = A3 + b4.w;
    ((float4*)out)[(size_t)t * 16 + q] = make_float4(v0, v1, v2, v3);

    // block BN reduction: channel c = q*4+j, slot = wv*4+g (16 slots)
    __shared__ float sb1[64][17];
    __shared__ float sb2[64][17];
    const int slot = wv * 4 + g;
    sb1[q * 4 + 0][slot] = v0; sb1[q * 4 + 1][slot] = v1;
    sb1[q * 4 + 2][slot] = v2; sb1[q * 4 + 3][slot] = v3;
    sb2[q * 4 + 0][slot] = v0 * v0; sb2[q * 4 + 1][slot] = v1 * v1;
    sb2[q * 4 + 2][slot] = v2 * v2; sb2[q * 4 + 3][slot] = v3 * v3;
    __syncthreads();
    if (tid < 64) {
        float t1 = 0.f, t2 = 0.f;
#pragma unroll
        for (int r = 0; r < 16; ++r) { t1 += sb1[tid][r]; t2 += sb2[tid][r]; }
        atomicAdd(&sums[tid], t1);
        atomicAdd(&sums[64 + tid], t2);
    }
}

// K4: BN stats computed redundantly per block from sums, then apply + ReLU.
__global__ __launch_bounds__(256) void k4_bn(
    float* __restrict__ out, const float* __restrict__ sums,
    const float* __restrict__ gamma, const float* __restrict__ beta)
{
    __shared__ float s_sc[64], s_sh[64];
    const int tid = threadIdx.x;
    if (tid < 64) {
        const float mu = sums[tid] / (float)NN;
        const float ex2 = sums[64 + tid] / (float)NN;
        const float var = fmaxf(ex2 - mu * mu, 0.f);
        const float sc = gamma[tid] / sqrtf(var + BN_EPS);
        s_sc[tid] = sc;
        s_sh[tid] = beta[tid] - mu * sc;
    }
    __syncthreads();
    const int total = NN * OUT_C / 4;
    float4* p = (float4*)out;
    for (int idx = blockIdx.x * 256 + tid; idx < total; idx += gridDim.x * 256) {
        float4 v = p[idx];
        const int c0 = (idx & 15) * 4;
        v.x = fmaxf(fmaf(v.x, s_sc[c0 + 0], s_sh[c0 + 0]), 0.f);
        v.y = fmaxf(fmaf(v.y, s_sc[c0 + 1], s_sh[c0 + 1]), 0.f);
        v.z = fmaxf(fmaf(v.z, s_sc[c0 + 2], s_sh[c0 + 2]), 0.f);
        v.w = fmaxf(fmaf(v.w, s_sc[c0 + 3], s_sh[c0 + 3]), 0.f);
        p[idx] = v;
    }
}

extern "C" void kernel_launch(void* const* d_in, const int* in_sizes, int n_in,
                              void* d_out, int out_size, void* d_ws, size_t ws_size,
                              hipStream_t stream) {
    const float* x        = (const float*)d_in[0];
    const float* emb      = (const float*)d_in[1];
    const int*   edge     = (const int*)d_in[2];   // row 0 = src
    const float* lin_w    = (const float*)d_in[3];
    const float* att_i    = (const float*)d_in[4];
    const float* att_j    = (const float*)d_in[5];
    const float* att_em_i = (const float*)d_in[6];
    const float* att_em_j = (const float*)d_in[7];
    const float* bias     = (const float*)d_in[8];
    const float* gamma    = (const float*)d_in[9];
    const float* beta     = (const float*)d_in[10];

    float* ws    = (float*)d_ws;
    unsigned short* x_bf = (unsigned short*)(ws + WS_XBF);
    float* a_i   = ws + WS_AI;
    float* a_j   = ws + WS_AJ;
    float* sums  = ws + WS_SUMS;
    float* out   = (float*)d_out;

    k1_mfma<<<K1_BLOCKS, 256, 0, stream>>>(x, emb, lin_w, att_i, att_j,
                                           att_em_i, att_em_j, x_bf, a_i, a_j, sums);
    k2_attn<<<K2_BLOCKS, 256, 0, stream>>>(edge, (const uint2*)x_bf, a_i, a_j,
                                           bias, out, sums);
    k4_bn<<<1024, 256, 0, stream>>>(out, sums, gamma, beta);
}

// Round 10
// 163.414 us; speedup vs baseline: 1.3299x; 1.2805x over previous
//
#include <hip/hip_runtime.h>

#define NN 50000
#define TOPK 32
#define IN_C 128
#define OUT_C 64
#define NEG_SLOPE 0.2f
#define BN_EPS 1e-5f

// K1: MFMA, 16 nodes per block
#define K1_BLOCKS (NN / 16)         // 3125
// K2: 64-thread blocks, 1 wave = 8 nodes (8 lanes x 16B = full row)
#define K2_BLOCKS (NN / 8)          // 6250

// workspace layout (floats)
#define WS_XBF   0                       // bf16 x_lin: NN*64*2B
#define WS_AI    (NN * 32)
#define WS_AJ    (WS_AI + NN)
#define WS_SUMS  (WS_AJ + NN)            // 8 replicas x 128

typedef __bf16 bf16x8 __attribute__((ext_vector_type(8)));
typedef float f32x4 __attribute__((ext_vector_type(4)));
union BF8 { unsigned short u[8]; bf16x8 v; };

__device__ inline float leaky(float a) { return a >= 0.f ? a : NEG_SLOPE * a; }
__device__ inline float bl(unsigned u) { return __uint_as_float(u << 16); }
__device__ inline float bh(unsigned u) { return __uint_as_float(u & 0xffff0000u); }

__device__ inline unsigned short f2bf(float f) {     // RNE fp32 -> bf16
    unsigned u = __float_as_uint(f);
    unsigned r = (u + 0x7fffu + ((u >> 16) & 1u)) >> 16;
    return (unsigned short)r;
}

// async global->LDS, 16 B per lane; LDS dest = base + lane*16 (HW rule)
__device__ inline void async16(const uint4* g, uint4* l) {
    __builtin_amdgcn_global_load_lds(
        (const __attribute__((address_space(1))) void*)(const void*)g,
        (__attribute__((address_space(3))) void*)(void*)l, 16, 0, 0);
}

// K1: x_lin(bf16) = x @ lin_w^T via MFMA 16x16x32_bf16 + a_i/a_j epilogue.
// (frozen from round 7; sums zeroing widened to 8 replicas)
__global__ __launch_bounds__(256) void k1_mfma(
    const float* __restrict__ x, const float* __restrict__ emb,
    const float* __restrict__ lin_w,
    const float* __restrict__ att_i, const float* __restrict__ att_j,
    const float* __restrict__ att_em_i, const float* __restrict__ att_em_j,
    unsigned short* __restrict__ x_bf, float* __restrict__ a_i,
    float* __restrict__ a_j, float* __restrict__ sums)
{
    __shared__ float redi[16][5], redj[16][5];
    __shared__ float eredi[16][17], eredj[16][17];
    const int tid = threadIdx.x;
    if (blockIdx.x == 0) {
#pragma unroll
        for (int i = 0; i < 4; ++i) sums[tid + i * 256] = 0.f;
    }

    const int lane = tid & 63;
    const int wv = tid >> 6;
    const int quad = lane >> 4;
    const int nn = lane & 15;
    const int base = blockIdx.x * 16;
    const int c = wv * 16 + nn;          // this lane's output channel

    BF8 bfr[4], afr[4];
    {
        const float* wr = lin_w + (size_t)c * IN_C + quad * 8;
        const float* xr = x + (size_t)(base + nn) * IN_C + quad * 8;
#pragma unroll
        for (int s = 0; s < 4; ++s) {
            const float4 wa = *(const float4*)(wr + s * 32);
            const float4 wb = *(const float4*)(wr + s * 32 + 4);
            const float4 xa = *(const float4*)(xr + s * 32);
            const float4 xb = *(const float4*)(xr + s * 32 + 4);
            bfr[s].u[0] = f2bf(wa.x); bfr[s].u[1] = f2bf(wa.y);
            bfr[s].u[2] = f2bf(wa.z); bfr[s].u[3] = f2bf(wa.w);
            bfr[s].u[4] = f2bf(wb.x); bfr[s].u[5] = f2bf(wb.y);
            bfr[s].u[6] = f2bf(wb.z); bfr[s].u[7] = f2bf(wb.w);
            afr[s].u[0] = f2bf(xa.x); afr[s].u[1] = f2bf(xa.y);
            afr[s].u[2] = f2bf(xa.z); afr[s].u[3] = f2bf(xa.w);
            afr[s].u[4] = f2bf(xb.x); afr[s].u[5] = f2bf(xb.y);
            afr[s].u[6] = f2bf(xb.z); afr[s].u[7] = f2bf(xb.w);
        }
    }

    f32x4 acc = {0.f, 0.f, 0.f, 0.f};
#pragma unroll
    for (int s = 0; s < 4; ++s)
        acc = __builtin_amdgcn_mfma_f32_16x16x32_bf16(afr[s].v, bfr[s].v, acc,
                                                      0, 0, 0);

    const float aic = att_i[c], ajc = att_j[c];
    float pi[4], pj[4];
#pragma unroll
    for (int r = 0; r < 4; ++r) {
        const int node = base + quad * 4 + r;
        x_bf[(size_t)node * OUT_C + c] = f2bf(acc[r]);
        pi[r] = acc[r] * aic;
        pj[r] = acc[r] * ajc;
    }
#pragma unroll
    for (int d = 1; d < 16; d <<= 1) {
#pragma unroll
        for (int r = 0; r < 4; ++r) {
            pi[r] += __shfl_xor(pi[r], d, 64);
            pj[r] += __shfl_xor(pj[r], d, 64);
        }
    }
    if (nn == 0) {
#pragma unroll
        for (int r = 0; r < 4; ++r) {
            redi[quad * 4 + r][wv] = pi[r];
            redj[quad * 4 + r][wv] = pj[r];
        }
    }
    {
        const int nl = tid >> 4, c4 = tid & 15;
        const float4 e4 = ((const float4*)emb)[(size_t)(base + nl) * 16 + c4];
        const float4 i4 = ((const float4*)att_em_i)[c4];
        const float4 j4 = ((const float4*)att_em_j)[c4];
        eredi[nl][c4] = e4.x * i4.x + e4.y * i4.y + e4.z * i4.z + e4.w * i4.w;
        eredj[nl][c4] = e4.x * j4.x + e4.y * j4.y + e4.z * j4.z + e4.w * j4.w;
    }
    __syncthreads();
    if (tid < 16) {
        float si = redi[tid][0] + redi[tid][1] + redi[tid][2] + redi[tid][3];
        float sj = redj[tid][0] + redj[tid][1] + redj[tid][2] + redj[tid][3];
#pragma unroll
        for (int r = 0; r < 16; ++r) { si += eredi[tid][r]; sj += eredj[tid][r]; }
        a_i[base + tid] = si;
        a_j[base + tid] = sj;
    }
}

// K2: one wave per block, 8 nodes per wave (lane = g*8+q: node g, 16B row
// slice q = channels q*8..q*8+7). All 33 row-gathers issued as
// global_load_lds (no VGPR dest -> all in flight at once), one vmcnt(0)
// drain, then consume from LDS. Softmax 8-lane partitioned; weights cross
// lanes via small LDS buffer. BN partials atomicAdd to 1-of-8 sum replicas.
__global__ __launch_bounds__(64) void k2_attn(
    const int* __restrict__ src, const uint4* __restrict__ x_bf4,
    const float* __restrict__ a_j, const float* __restrict__ a_i,
    const float* __restrict__ bias, float* __restrict__ out,
    float* __restrict__ sums)
{
    __shared__ uint4 stage[33 * 64];     // 33 KB staged rows
    __shared__ float wbuf[8][36];        // per-node 33 weights (+pad)
    __shared__ float sb1[64][9], sb2[64][9];

    const int tid = threadIdx.x;         // == lane (64-thread block)
    const int g = tid >> 3;              // node within group of 8
    const int q = tid & 7;               // row slice
    const int t = blockIdx.x * 8 + g;

    // all 32 src indices of this lane's node (broadcast across its 8 lanes)
    const int4* sp4 = (const int4*)(src + (size_t)t * TOPK);
    int4 s4[8];
#pragma unroll
    for (int i = 0; i < 8; ++i) s4[i] = sp4[i];
    const int4 sq = sp4[q];              // this lane's softmax partition

    // issue all 33 gathers: edge e of each node -> stage[e*64 + lane]
#pragma unroll
    for (int i = 0; i < 8; ++i) {
        async16(x_bf4 + ((size_t)s4[i].x * 8 + q), &stage[(i * 4 + 0) * 64]);
        async16(x_bf4 + ((size_t)s4[i].y * 8 + q), &stage[(i * 4 + 1) * 64]);
        async16(x_bf4 + ((size_t)s4[i].z * 8 + q), &stage[(i * 4 + 2) * 64]);
        async16(x_bf4 + ((size_t)s4[i].w * 8 + q), &stage[(i * 4 + 3) * 64]);
    }
    async16(x_bf4 + ((size_t)t * 8 + q), &stage[32 * 64]);   // self row

    // softmax over 33 edges: lane q owns edges q*4..q*4+3
    const float ai_t = a_i[t];
    float l0 = leaky(ai_t + a_j[sq.x]);
    float l1 = leaky(ai_t + a_j[sq.y]);
    float l2 = leaky(ai_t + a_j[sq.z]);
    float l3 = leaky(ai_t + a_j[sq.w]);
    const float ls = leaky(ai_t + a_j[t]);
    float mx = fmaxf(fmaxf(l0, l1), fmaxf(l2, l3));
#pragma unroll
    for (int d = 1; d < 8; d <<= 1) mx = fmaxf(mx, __shfl_xor(mx, d, 64));
    mx = fmaxf(mx, ls);
    const float e0 = __expf(l0 - mx), e1 = __expf(l1 - mx);
    const float e2 = __expf(l2 - mx), e3 = __expf(l3 - mx);
    const float es = __expf(ls - mx);
    float den = (e0 + e1) + (e2 + e3);
#pragma unroll
    for (int d = 1; d < 8; d <<= 1) den += __shfl_xor(den, d, 64);
    den += es + 1e-16f;
    const float inv = 1.f / den;

    ((float4*)&wbuf[g][q * 4])[0] =
        make_float4(e0 * inv, e1 * inv, e2 * inv, e3 * inv);
    if (q == 0) wbuf[g][32] = es * inv;
    __syncthreads();                      // single wave: cheap

    float4 w4[8];
#pragma unroll
    for (int i = 0; i < 8; ++i) w4[i] = ((const float4*)wbuf[g])[i];
    const float wself = wbuf[g][32];

    __builtin_amdgcn_s_waitcnt(0x0F70);   // vmcnt(0): all staged rows ready
    __syncthreads();

    float A[8];
#pragma unroll
    for (int j = 0; j < 8; ++j) A[j] = 0.f;
#pragma unroll
    for (int e = 0; e < 33; ++e) {
        const uint4 u = stage[e * 64 + tid];
        const float w = (e < 32) ? ((const float*)&w4[e >> 2])[e & 3] : wself;
        A[0] = fmaf(w, bl(u.x), A[0]); A[1] = fmaf(w, bh(u.x), A[1]);
        A[2] = fmaf(w, bl(u.y), A[2]); A[3] = fmaf(w, bh(u.y), A[3]);
        A[4] = fmaf(w, bl(u.z), A[4]); A[5] = fmaf(w, bh(u.z), A[5]);
        A[6] = fmaf(w, bl(u.w), A[6]); A[7] = fmaf(w, bh(u.w), A[7]);
    }
    const float4 b0 = ((const float4*)bias)[q * 2];
    const float4 b1 = ((const float4*)bias)[q * 2 + 1];
    float v[8];
    v[0] = A[0] + b0.x; v[1] = A[1] + b0.y; v[2] = A[2] + b0.z; v[3] = A[3] + b0.w;
    v[4] = A[4] + b1.x; v[5] = A[5] + b1.y; v[6] = A[6] + b1.z; v[7] = A[7] + b1.w;
    float4* o4 = (float4*)(out + (size_t)t * OUT_C + q * 8);
    o4[0] = make_float4(v[0], v[1], v[2], v[3]);
    o4[1] = make_float4(v[4], v[5], v[6], v[7]);

    // BN partials: channel c = q*8+j, reduce over the 8 nodes (col g)
#pragma unroll
    for (int j = 0; j < 8; ++j) {
        sb1[q * 8 + j][g] = v[j];
        sb2[q * 8 + j][g] = v[j] * v[j];
    }
    __syncthreads();
    {
        float t1 = 0.f, t2 = 0.f;
#pragma unroll
        for (int r = 0; r < 8; ++r) { t1 += sb1[tid][r]; t2 += sb2[tid][r]; }
        float* rep = sums + (blockIdx.x & 7) * 128;
        atomicAdd(&rep[tid], t1);
        atomicAdd(&rep[64 + tid], t2);
    }
}

// K4: BN stats from the 8 sum replicas (redundant per block), apply + ReLU.
__global__ __launch_bounds__(256) void k4_bn(
    float* __restrict__ out, const float* __restrict__ sums,
    const float* __restrict__ gamma, const float* __restrict__ beta)
{
    __shared__ float s_sc[64], s_sh[64];
    const int tid = threadIdx.x;
    if (tid < 64) {
        float s1 = 0.f, s2 = 0.f;
#pragma unroll
        for (int r = 0; r < 8; ++r) {
            s1 += sums[r * 128 + tid];
            s2 += sums[r * 128 + 64 + tid];
        }
        const float mu = s1 / (float)NN;
        const float ex2 = s2 / (float)NN;
        const float var = fmaxf(ex2 - mu * mu, 0.f);
        const float sc = gamma[tid] / sqrtf(var + BN_EPS);
        s_sc[tid] = sc;
        s_sh[tid] = beta[tid] - mu * sc;
    }
    __syncthreads();
    const int total = NN * OUT_C / 4;
    float4* p = (float4*)out;
    for (int idx = blockIdx.x * 256 + tid; idx < total; idx += gridDim.x * 256) {
        float4 v = p[idx];
        const int c0 = (idx & 15) * 4;
        v.x = fmaxf(fmaf(v.x, s_sc[c0 + 0], s_sh[c0 + 0]), 0.f);
        v.y = fmaxf(fmaf(v.y, s_sc[c0 + 1], s_sh[c0 + 1]), 0.f);
        v.z = fmaxf(fmaf(v.z, s_sc[c0 + 2], s_sh[c0 + 2]), 0.f);
        v.w = fmaxf(fmaf(v.w, s_sc[c0 + 3], s_sh[c0 + 3]), 0.f);
        p[idx] = v;
    }
}

extern "C" void kernel_launch(void* const* d_in, const int* in_sizes, int n_in,
                              void* d_out, int out_size, void* d_ws, size_t ws_size,
                              hipStream_t stream) {
    const float* x        = (const float*)d_in[0];
    const float* emb      = (const float*)d_in[1];
    const int*   edge     = (const int*)d_in[2];   // row 0 = src
    const float* lin_w    = (const float*)d_in[3];
    const float* att_i    = (const float*)d_in[4];
    const float* att_j    = (const float*)d_in[5];
    const float* att_em_i = (const float*)d_in[6];
    const float* att_em_j = (const float*)d_in[7];
    const float* bias     = (const float*)d_in[8];
    const float* gamma    = (const float*)d_in[9];
    const float* beta     = (const float*)d_in[10];

    float* ws    = (float*)d_ws;
    unsigned short* x_bf = (unsigned short*)(ws + WS_XBF);
    float* a_i   = ws + WS_AI;
    float* a_j   = ws + WS_AJ;
    float* sums  = ws + WS_SUMS;
    float* out   = (float*)d_out;

    k1_mfma<<<K1_BLOCKS, 256, 0, stream>>>(x, emb, lin_w, att_i, att_j,
                                           att_em_i, att_em_j, x_bf, a_i, a_j, sums);
    k2_attn<<<K2_BLOCKS, 64, 0, stream>>>(edge, (const uint4*)x_bf, a_j, a_i,
                                          bias, out, sums);
    k4_bn<<<1024, 256, 0, stream>>>(out, sums, gamma, beta);
}